// Round 1
// baseline (306.760 us; speedup 1.0000x reference)
//
#include <hip/hip_runtime.h>
#include <hip/hip_bf16.h>
#include <stdint.h>

#define BATCH 4
#define SEQ   4096
#define EMB   1024
#define HD    64
#define NROW  (BATCH*SEQ)   // 16384

typedef __bf16 bf16x8 __attribute__((ext_vector_type(8)));
typedef float  f32x4  __attribute__((ext_vector_type(4)));
typedef unsigned short u16;

union ABFrag { u16 s[8]; bf16x8 v; };

__device__ __forceinline__ u16 f2bf_rne(float f) {
    union { float f; uint32_t u; } cv; cv.f = f;
    uint32_t u = cv.u;
    return (u16)((u + 0x7fffu + ((u >> 16) & 1u)) >> 16);
}

// ---------------------------------------------------------------------------
// Kernel 0: W (1024,64) fp32 x3 -> Wt bf16 [3][64][1024]  (transposed)
// ---------------------------------------------------------------------------
__global__ __launch_bounds__(256) void wt_kernel(
        const float* __restrict__ Wq, const float* __restrict__ Wk,
        const float* __restrict__ Wv, u16* __restrict__ Wt) {
    int idx = blockIdx.x * 256 + threadIdx.x;   // 0 .. 3*65536-1
    int i = idx >> 16;
    int r = idx & 65535;
    int n = r >> 10;      // 0..63  (head dim)
    int k = r & 1023;     // 0..1023 (embed dim)
    const float* W = (i == 0) ? Wq : (i == 1) ? Wk : Wv;
    Wt[idx] = f2bf_rne(W[k * HD + n]);
}

// ---------------------------------------------------------------------------
// Kernel 1: QKV projection.  x (16384,1024) fp32 @ Wt -> Qw/Kw (row-major bf16,
// Q pre-scaled by 2^-5) and Vt (bf16, [b][64][T] transposed).
// Block = 4 waves; wave computes 16 rows x 64 cols for all 3 weights.
// ---------------------------------------------------------------------------
__global__ __launch_bounds__(256) void qkv_kernel(
        const float* __restrict__ x, const u16* __restrict__ Wt,
        u16* __restrict__ Qw, u16* __restrict__ Kw, u16* __restrict__ Vt) {
    const int wave = threadIdx.x >> 6;
    const int lane = threadIdx.x & 63;
    const int m16  = lane & 15;
    const int quad = lane >> 4;
    const int row  = blockIdx.x * 64 + wave * 16 + m16;   // 0..16383

    f32x4 acc[3][4];
#pragma unroll
    for (int w3 = 0; w3 < 3; ++w3)
#pragma unroll
        for (int nt = 0; nt < 4; ++nt)
            acc[w3][nt] = (f32x4){0.f, 0.f, 0.f, 0.f};

    const float* xrow = x + (size_t)row * EMB + (quad << 3);
    const u16*   wtl  = Wt + (m16 << 10) + (quad << 3);  // row = m16 (+16*nt)

    for (int ks = 0; ks < 32; ++ks) {
        float4 a0 = *(const float4*)(xrow + (ks << 5));
        float4 a1 = *(const float4*)(xrow + (ks << 5) + 4);
        ABFrag af;
        af.s[0] = f2bf_rne(a0.x); af.s[1] = f2bf_rne(a0.y);
        af.s[2] = f2bf_rne(a0.z); af.s[3] = f2bf_rne(a0.w);
        af.s[4] = f2bf_rne(a1.x); af.s[5] = f2bf_rne(a1.y);
        af.s[6] = f2bf_rne(a1.z); af.s[7] = f2bf_rne(a1.w);
#pragma unroll
        for (int w3 = 0; w3 < 3; ++w3) {
#pragma unroll
            for (int nt = 0; nt < 4; ++nt) {
                bf16x8 bf = *(const bf16x8*)(wtl + (w3 << 16) + (nt << 14) + (ks << 5));
                acc[w3][nt] = __builtin_amdgcn_mfma_f32_16x16x32_bf16(
                        af.v, bf, acc[w3][nt], 0, 0, 0);
            }
        }
    }

    // C layout: lane holds rows quad*4+reg (in-tile), col = m16 + 16*nt
    const int rowbase = blockIdx.x * 64 + wave * 16 + (quad << 2);
    const int bidx = rowbase >> 12;          // batch
    const int t0   = rowbase & 4095;         // position within batch
#pragma unroll
    for (int nt = 0; nt < 4; ++nt) {
        const int col = m16 + (nt << 4);
        // Q (scaled by 2^-5) and K: row-major scalar u16 stores
#pragma unroll
        for (int reg = 0; reg < 4; ++reg) {
            size_t o = (size_t)(rowbase + reg) * HD + col;
            Qw[o] = f2bf_rne(acc[0][nt][reg] * 0.03125f);
            Kw[o] = f2bf_rne(acc[1][nt][reg]);
        }
        // V transposed: 4 consecutive t -> one 8B store
        ushort4 vv;
        vv.x = f2bf_rne(acc[2][nt][0]); vv.y = f2bf_rne(acc[2][nt][1]);
        vv.z = f2bf_rne(acc[2][nt][2]); vv.w = f2bf_rne(acc[2][nt][3]);
        *(ushort4*)(Vt + (size_t)((bidx << 6) + col) * SEQ + t0) = vv;
    }
}

// ---------------------------------------------------------------------------
// Kernel 2: causal flash attention. Block = 4 waves = 64 Q rows (16/wave).
// KV tiles of 64. Wave-private LDS P buffer (16x64, row stride 72 to avoid
// bank conflicts) for the C-layout -> A-layout transform.
// ---------------------------------------------------------------------------
__global__ __launch_bounds__(256) void attn_kernel(
        const u16* __restrict__ Qw, const u16* __restrict__ Kw,
        const u16* __restrict__ Vt, float* __restrict__ out) {
    __shared__ u16 ldsP[4][16 * 72];

    const int wave = threadIdx.x >> 6;
    const int lane = threadIdx.x & 63;
    const int m16  = lane & 15;
    const int quad = lane >> 4;
    const int b  = blockIdx.x >> 6;
    const int qt = blockIdx.x & 63;

    // Q fragments (A layout: m = lane&15, k = quad*8+j), resident for the block
    const int qrow = (qt << 6) + (wave << 4) + m16;
    const u16* qbase = Qw + ((size_t)(b * SEQ + qrow) << 6);
    const bf16x8 qf0 = *(const bf16x8*)(qbase + (quad << 3));
    const bf16x8 qf1 = *(const bf16x8*)(qbase + 32 + (quad << 3));

    f32x4 acc_o[4];
#pragma unroll
    for (int nt = 0; nt < 4; ++nt) acc_o[nt] = (f32x4){0.f, 0.f, 0.f, 0.f};
    float m_i[4] = {-3.0e38f, -3.0e38f, -3.0e38f, -3.0e38f};
    float l_i[4] = {0.f, 0.f, 0.f, 0.f};

    u16* ldsW = &ldsP[wave][0];

    for (int jt = 0; jt <= qt; ++jt) {
        // ---- S = Q @ K^T (scale folded into Q) ----
        f32x4 s[4];
#pragma unroll
        for (int nt = 0; nt < 4; ++nt) s[nt] = (f32x4){0.f, 0.f, 0.f, 0.f};
        const u16* kbase = Kw + ((size_t)(b * SEQ + (jt << 6) + m16) << 6) + (quad << 3);
#pragma unroll
        for (int nt = 0; nt < 4; ++nt) {
            bf16x8 k0 = *(const bf16x8*)(kbase + (nt << 10));
            bf16x8 k1 = *(const bf16x8*)(kbase + (nt << 10) + 32);
            s[nt] = __builtin_amdgcn_mfma_f32_16x16x32_bf16(qf0, k0, s[nt], 0, 0, 0);
            s[nt] = __builtin_amdgcn_mfma_f32_16x16x32_bf16(qf1, k1, s[nt], 0, 0, 0);
        }

        // ---- causal mask on diagonal tile ----
        if (jt == qt) {
            const int rowin = (wave << 4) + (quad << 2);
#pragma unroll
            for (int nt = 0; nt < 4; ++nt) {
                const int colin = m16 + (nt << 4);
#pragma unroll
                for (int reg = 0; reg < 4; ++reg)
                    if (colin > rowin + reg) s[nt][reg] = -3.0e38f;
            }
        }

        // ---- online softmax (rows live in 16-lane quads) ----
#pragma unroll
        for (int reg = 0; reg < 4; ++reg) {
            float mx = fmaxf(fmaxf(s[0][reg], s[1][reg]), fmaxf(s[2][reg], s[3][reg]));
            mx = fmaxf(mx, __shfl_xor(mx, 1));
            mx = fmaxf(mx, __shfl_xor(mx, 2));
            mx = fmaxf(mx, __shfl_xor(mx, 4));
            mx = fmaxf(mx, __shfl_xor(mx, 8));
            const float mnew  = fmaxf(m_i[reg], mx);
            const float alpha = __expf(m_i[reg] - mnew);
            m_i[reg] = mnew;
            float psum = 0.f;
            u16* lp = ldsW + ((quad << 2) + reg) * 72 + m16;
#pragma unroll
            for (int nt = 0; nt < 4; ++nt) {
                const float p = __expf(s[nt][reg] - mnew);
                psum += p;
                lp[nt << 4] = f2bf_rne(p);
                acc_o[nt][reg] *= alpha;
            }
            l_i[reg] = alpha * l_i[reg] + psum;
        }

        // ---- O += P @ V  (P via LDS round-trip to A layout) ----
        const bf16x8 p0 = *(const bf16x8*)(ldsW + m16 * 72 + (quad << 3));
        const bf16x8 p1 = *(const bf16x8*)(ldsW + m16 * 72 + 32 + (quad << 3));
        const u16* vb = Vt + (size_t)((b << 6) + m16) * SEQ + (jt << 6) + (quad << 3);
#pragma unroll
        for (int nt = 0; nt < 4; ++nt) {
            bf16x8 v0 = *(const bf16x8*)(vb + nt * 16 * SEQ);
            bf16x8 v1 = *(const bf16x8*)(vb + nt * 16 * SEQ + 32);
            acc_o[nt] = __builtin_amdgcn_mfma_f32_16x16x32_bf16(p0, v0, acc_o[nt], 0, 0, 0);
            acc_o[nt] = __builtin_amdgcn_mfma_f32_16x16x32_bf16(p1, v1, acc_o[nt], 0, 0, 0);
        }
    }

    // ---- finalize: reduce l over the quad's 16 lanes, divide, store fp32 ----
#pragma unroll
    for (int reg = 0; reg < 4; ++reg) {
        float l = l_i[reg];
        l += __shfl_xor(l, 1);
        l += __shfl_xor(l, 2);
        l += __shfl_xor(l, 4);
        l += __shfl_xor(l, 8);
        const float rinv = 1.0f / l;
        const int rowb = (qt << 6) + (wave << 4) + (quad << 2) + reg;
        float* ob = out + ((size_t)(b * SEQ + rowb) << 6) + m16;
#pragma unroll
        for (int nt = 0; nt < 4; ++nt) ob[nt << 4] = acc_o[nt][reg] * rinv;
    }
}

// ---------------------------------------------------------------------------
extern "C" void kernel_launch(void* const* d_in, const int* in_sizes, int n_in,
                              void* d_out, int out_size, void* d_ws, size_t ws_size,
                              hipStream_t stream) {
    const float* x  = (const float*)d_in[0];
    const float* Wq = (const float*)d_in[1];
    const float* Wk = (const float*)d_in[2];
    const float* Wv = (const float*)d_in[3];
    float* out = (float*)d_out;

    u16* ws = (u16*)d_ws;
    u16* Qw = ws;                      // 16384*64 bf16 = 2 MB
    u16* Kw = ws + (1u << 20);         // 2 MB
    u16* Vt = ws + (2u << 20);         // 2 MB  ([b][64][T])
    u16* Wt = ws + (3u << 20);         // 3*64*1024 bf16 = 384 KB

    wt_kernel<<<768, 256, 0, stream>>>(Wq, Wk, Wv, Wt);
    qkv_kernel<<<256, 256, 0, stream>>>(x, Wt, Qw, Kw, Vt);
    attn_kernel<<<256, 256, 0, stream>>>(Qw, Kw, Vt, out);
}